// Round 2
// baseline (344.606 us; speedup 1.0000x reference)
//
#include <hip/hip_runtime.h>
#include <hip/hip_bf16.h>

// Problem constants (fixed by the reference's setup_inputs)
#define BB 2
#define CC 256      // channels per level
#define HH 100
#define WW 100
#define NN 256      // rois per batch
#define KK (BB*NN)  // 512 total rois
#define C3 (3*CC)   // 768 fused channels
#define OUTB 7
#define SR 2
#define NSAMP (OUTB*SR)   // 14 sample positions per axis
#define BINS (OUTB*OUTB)  // 49

// ---------------------------------------------------------------------------
// build_F: fused (x0 | 2x-up x1 | 4x-up x2) feature, channel-last F[b][pos][c].
// LDS tile transpose: read side lane=pos (coalesced), write side float4 along c.
// Upsample matches jax.image.resize 'bilinear': src = (i+0.5)/s - 0.5, clamped.
// ---------------------------------------------------------------------------
__global__ __launch_bounds__(256) void build_F(const float* __restrict__ x0,
                                               const float* __restrict__ x1,
                                               const float* __restrict__ x2,
                                               float* __restrict__ F) {
    __shared__ float tile[64][65];           // [c_local][p_local], +1 pad
    const int ptile = blockIdx.x;            // 157 tiles of 64 positions
    const int ctile = blockIdx.y;            // 12 tiles of 64 channels
    const int b     = blockIdx.z;
    const int tid   = threadIdx.x;
    const int lane  = tid & 63;
    const int grp   = tid >> 6;              // 0..3

    const int pos = ptile*64 + lane;         // constant per thread
    const int level = ctile >> 2;            // 0: x0, 1: x1(2x), 2: x2(4x)
    const int cbase = (ctile & 3) * 64;      // channel offset within level

    if (pos < HH*WW) {
        if (level == 0) {
            const float* p = x0 + (size_t)b*CC*(HH*WW) + pos;
            #pragma unroll
            for (int r = 0; r < 16; ++r) {
                int c_local = r*4 + grp;
                tile[c_local][lane] = p[(size_t)(cbase + c_local)*(HH*WW)];
            }
        } else {
            const int   L = (level == 1) ? 50 : 25;
            const float s = (level == 1) ? 0.5f  : 0.25f;
            const float t = (level == 1) ? 0.25f : 0.375f;
            const float* src = (level == 1) ? x1 : x2;
            const int y = pos / WW, x = pos - (pos / WW) * WW;
            float cy = fminf(fmaxf((float)y * s - t, 0.0f), (float)(L - 1));
            float cx = fminf(fmaxf((float)x * s - t, 0.0f), (float)(L - 1));
            int yl = (int)cy, xl = (int)cx;
            int yh = min(yl + 1, L - 1), xh = min(xl + 1, L - 1);
            float fy = cy - (float)yl, fx = cx - (float)xl;
            float w00 = (1.0f-fy)*(1.0f-fx), w01 = (1.0f-fy)*fx;
            float w10 = fy*(1.0f-fx),        w11 = fy*fx;
            int o00 = yl*L+xl, o01 = yl*L+xh, o10 = yh*L+xl, o11 = yh*L+xh;
            const float* p = src + ((size_t)b*CC + cbase)*(size_t)(L*L);
            #pragma unroll
            for (int r = 0; r < 16; ++r) {
                int c_local = r*4 + grp;
                const float* q = p + (size_t)c_local*(L*L);
                tile[c_local][lane] = q[o00]*w00 + q[o01]*w01 + q[o10]*w10 + q[o11]*w11;
            }
        }
    }
    __syncthreads();

    // write: 16 lanes x float4 along c, 4 pos rows per wave; 2-way LDS alias (free)
    #pragma unroll
    for (int r = 0; r < 4; ++r) {
        int p_local = r*16 + (tid >> 4);
        int pp = ptile*64 + p_local;
        if (pp < HH*WW) {
            int c4 = (tid & 15) * 4;
            float4 v = make_float4(tile[c4+0][p_local], tile[c4+1][p_local],
                                   tile[c4+2][p_local], tile[c4+3][p_local]);
            *(float4*)(F + ((size_t)b*(HH*WW) + pp)*C3 + ctile*64 + c4) = v;
        }
    }
}

// ---------------------------------------------------------------------------
// roi2: one block per (roi, oy). 192 threads, each owns 4 consecutive channels
// -> all corner gathers are float4 (coalesced 3KB/wave).
// ---------------------------------------------------------------------------
__global__ __launch_bounds__(192) void roi2(const float* __restrict__ F,
                                            const float* __restrict__ boxes,
                                            const float* __restrict__ ratio_hw,
                                            const float* __restrict__ offset_tl,
                                            float* __restrict__ out) {
    __shared__ int   s_xlo[NSAMP], s_xhi[NSAMP], s_vx[NSAMP];
    __shared__ float s_fx[NSAMP];
    __shared__ int   s_ylo[2], s_yhi[2], s_vy[2];
    __shared__ float s_fy[2];

    const int tid = threadIdx.x;
    const int k   = blockIdx.x;              // roi 0..511
    const int oy  = blockIdx.y;              // 0..6
    const int b   = k >> 8;                  // N=256

    if (tid < NSAMP + 2) {
        float r0 = ratio_hw[0], o0 = offset_tl[0];
        float scale = (float)HH / (1250.0f * r0 + 2.0f * o0);
        float rH  = ratio_hw[2*b],  rW   = ratio_hw[2*b + 1];
        float top = offset_tl[2*b], left = offset_tl[2*b + 1];
        const float* bx = boxes + (size_t)k * 4;
        bool isy = (tid >= NSAMP);
        int i = isy ? (oy*SR + tid - NSAMP) : tid;
        float a, e;
        if (isy) { a = (bx[1]*rH + top)*scale;  e = (bx[3]*rH + top)*scale;  }
        else     { a = (bx[0]*rW + left)*scale; e = (bx[2]*rW + left)*scale; }
        float len = fmaxf(e - a, 1.0f);          // ALIGNED=False
        float bs = len * (1.0f / (float)OUTB);
        float g = (float)(i >> 1) + 0.25f + 0.5f * (float)(i & 1);
        float p = a + g * bs;
        int v = (p >= -1.0f && p <= (float)HH) ? 1 : 0;
        float cc = fminf(fmaxf(p, 0.0f), (float)(HH - 1));
        int lo = (int)floorf(cc);
        int hi = min(lo + 1, HH - 1);
        float fr = cc - (float)lo;
        if (isy) { s_ylo[i - oy*SR] = lo; s_yhi[i - oy*SR] = hi; s_fy[i - oy*SR] = fr; s_vy[i - oy*SR] = v; }
        else     { s_xlo[i] = lo; s_xhi[i] = hi; s_fx[i] = fr; s_vx[i] = v; }
    }
    __syncthreads();

    const float4* Fb = (const float4*)(F + (size_t)b*(HH*WW)*C3);  // 192 float4 per pos
    float* outk = out + (size_t)k*C3*BINS;

    for (int ox = 0; ox < OUTB; ++ox) {
        float4 acc = make_float4(0.f, 0.f, 0.f, 0.f);
        #pragma unroll
        for (int sy = 0; sy < SR; ++sy) {
            const int yl = s_ylo[sy], yh = s_yhi[sy];
            const float fy = s_fy[sy];
            const int vy = s_vy[sy];
            #pragma unroll
            for (int sx = 0; sx < SR; ++sx) {
                const int ix = ox*SR + sx;
                if (vy && s_vx[ix]) {
                    const int xl = s_xlo[ix], xh = s_xhi[ix];
                    const float fx = s_fx[ix];
                    const float hy = 1.0f - fy, hx = 1.0f - fx;
                    const float w00 = hy*hx, w01 = hy*fx, w10 = fy*hx, w11 = fy*fx;
                    float4 v00 = Fb[(size_t)(yl*WW + xl)*192 + tid];
                    float4 v01 = Fb[(size_t)(yl*WW + xh)*192 + tid];
                    float4 v10 = Fb[(size_t)(yh*WW + xl)*192 + tid];
                    float4 v11 = Fb[(size_t)(yh*WW + xh)*192 + tid];
                    acc.x += v00.x*w00 + v01.x*w01 + v10.x*w10 + v11.x*w11;
                    acc.y += v00.y*w00 + v01.y*w01 + v10.y*w10 + v11.y*w11;
                    acc.z += v00.z*w00 + v01.z*w01 + v10.z*w10 + v11.z*w11;
                    acc.w += v00.w*w00 + v01.w*w01 + v10.w*w10 + v11.w*w11;
                }
            }
        }
        const size_t base = (size_t)(tid*4)*BINS + oy*OUTB + ox;
        outk[base + 0*BINS] = acc.x * 0.25f;
        outk[base + 1*BINS] = acc.y * 0.25f;
        outk[base + 2*BINS] = acc.z * 0.25f;
        outk[base + 3*BINS] = acc.w * 0.25f;
    }
}

// ---------------------------------------------------------------------------
// Fallback (no workspace): direct gather from sources, one float per thread.
// ---------------------------------------------------------------------------
__device__ __forceinline__ float feat_val(const float* __restrict__ x0,
                                          const float* __restrict__ x1,
                                          const float* __restrict__ x2,
                                          int b, int y, int x, int c) {
    if (c < CC) {
        return x0[(((size_t)b*CC + c)*HH + y)*WW + x];
    }
    const float* src;
    int L; float s, t; int cl;
    if (c < 2*CC) { src = x1; L = 50; s = 0.5f;  t = 0.25f;  cl = c - CC; }
    else          { src = x2; L = 25; s = 0.25f; t = 0.375f; cl = c - 2*CC; }
    float cy = fminf(fmaxf((float)y * s - t, 0.0f), (float)(L - 1));
    float cx = fminf(fmaxf((float)x * s - t, 0.0f), (float)(L - 1));
    int yl = (int)cy, xl = (int)cx;
    int yh = min(yl + 1, L - 1), xh = min(xl + 1, L - 1);
    float fy = cy - (float)yl, fx = cx - (float)xl;
    const float* p = src + (((size_t)b*CC + cl)*L)*L;
    float v00 = p[yl*L + xl], v01 = p[yl*L + xh];
    float v10 = p[yh*L + xl], v11 = p[yh*L + xh];
    float hy = 1.0f - fy, hx = 1.0f - fx;
    return v00*(hy*hx) + v01*(hy*fx) + v10*(fy*hx) + v11*(fy*fx);
}

__global__ __launch_bounds__(256) void roi_fallback(const float* __restrict__ x0,
                                                    const float* __restrict__ x1,
                                                    const float* __restrict__ x2,
                                                    const float* __restrict__ boxes,
                                                    const float* __restrict__ ratio_hw,
                                                    const float* __restrict__ offset_tl,
                                                    float* __restrict__ out) {
    __shared__ int   s_ylo[NSAMP], s_yhi[NSAMP], s_xlo[NSAMP], s_xhi[NSAMP];
    __shared__ float s_fy[NSAMP], s_fx[NSAMP];
    __shared__ int   s_vy[NSAMP], s_vx[NSAMP];

    const int tid = threadIdx.x;
    const int k = blockIdx.x;
    const int chunk = blockIdx.y;
    const int b = k >> 8;

    if (tid < 2*NSAMP) {
        float r0 = ratio_hw[0], o0 = offset_tl[0];
        float scale = (float)HH / (1250.0f * r0 + 2.0f * o0);
        float rH  = ratio_hw[2*b],  rW   = ratio_hw[2*b + 1];
        float top = offset_tl[2*b], left = offset_tl[2*b + 1];
        const float* bx = boxes + (size_t)k * 4;
        bool isx = (tid >= NSAMP);
        int i = isx ? tid - NSAMP : tid;
        float a, e;
        if (isx) { a = (bx[0]*rW + left)*scale; e = (bx[2]*rW + left)*scale; }
        else     { a = (bx[1]*rH + top)*scale;  e = (bx[3]*rH + top)*scale;  }
        float len = fmaxf(e - a, 1.0f);
        float bs = len * (1.0f / (float)OUTB);
        float g = (float)(i >> 1) + 0.25f + 0.5f * (float)(i & 1);
        float p = a + g * bs;
        int v = (p >= -1.0f && p <= (float)HH) ? 1 : 0;
        float cc = fminf(fmaxf(p, 0.0f), (float)(HH - 1));
        int lo = (int)floorf(cc);
        int hi = min(lo + 1, HH - 1);
        float fr = cc - (float)lo;
        if (isx) { s_xlo[i] = lo; s_xhi[i] = hi; s_fx[i] = fr; s_vx[i] = v; }
        else     { s_ylo[i] = lo; s_yhi[i] = hi; s_fy[i] = fr; s_vy[i] = v; }
    }
    __syncthreads();

    const int c = chunk * 256 + tid;
    for (int oy = 0; oy < OUTB; ++oy) {
        for (int ox = 0; ox < OUTB; ++ox) {
            float acc = 0.0f;
            #pragma unroll
            for (int sy = 0; sy < SR; ++sy) {
                const int iy = oy*SR + sy;
                #pragma unroll
                for (int sx = 0; sx < SR; ++sx) {
                    const int ix = ox*SR + sx;
                    if (s_vy[iy] && s_vx[ix]) {
                        const float fy = s_fy[iy], fx = s_fx[ix];
                        const float hy = 1.0f - fy, hx = 1.0f - fx;
                        float v00 = feat_val(x0,x1,x2,b, s_ylo[iy], s_xlo[ix], c);
                        float v01 = feat_val(x0,x1,x2,b, s_ylo[iy], s_xhi[ix], c);
                        float v10 = feat_val(x0,x1,x2,b, s_yhi[iy], s_xlo[ix], c);
                        float v11 = feat_val(x0,x1,x2,b, s_yhi[iy], s_xhi[ix], c);
                        acc += v00*(hy*hx) + v01*(hy*fx) + v10*(fy*hx) + v11*(fy*fx);
                    }
                }
            }
            out[(size_t)k*C3*BINS + (size_t)c*BINS + oy*OUTB + ox] = acc * 0.25f;
        }
    }
}

extern "C" void kernel_launch(void* const* d_in, const int* in_sizes, int n_in,
                              void* d_out, int out_size, void* d_ws, size_t ws_size,
                              hipStream_t stream) {
    const float* x0       = (const float*)d_in[0];
    const float* x1       = (const float*)d_in[1];
    const float* x2       = (const float*)d_in[2];
    const float* boxes    = (const float*)d_in[3];
    const float* ratio_hw = (const float*)d_in[4];
    const float* off_tl   = (const float*)d_in[5];
    float* out = (float*)d_out;

    const size_t needF = (size_t)BB * HH * WW * C3 * sizeof(float);  // 61.44 MB
    if (ws_size >= needF) {
        float* F = (float*)d_ws;
        build_F<<<dim3((HH*WW + 63)/64, C3/64, BB), 256, 0, stream>>>(x0, x1, x2, F);
        roi2<<<dim3(KK, OUTB), 192, 0, stream>>>(F, boxes, ratio_hw, off_tl, out);
    } else {
        roi_fallback<<<dim3(KK, 3), 256, 0, stream>>>(x0, x1, x2,
                                                      boxes, ratio_hw, off_tl, out);
    }
}

// Round 3
// 101.387 us; speedup vs baseline: 3.3989x; 3.3989x over previous
//
#include <hip/hip_runtime.h>
#include <hip/hip_bf16.h>

// Problem constants (fixed by the reference's setup_inputs)
#define BB 2
#define CC 256      // channels per level
#define HH 100
#define WW 100
#define NN 256      // rois per batch
#define KK (BB*NN)  // 512 total rois
#define C3 (3*CC)   // 768 fused channels
#define OUTB 7
#define SR 2
#define NSAMP (OUTB*SR)   // 14 sample positions per axis
#define BINS (OUTB*OUTB)  // 49

// LDS address swizzle: XOR bits 10-11 into bits 3-4 (bijective involution).
// Store side (c-strided, 8-way bank conflict) gets spread; read side
// (consecutive) stays conflict-free since bits 10-11 are constant per 128-run.
__device__ __forceinline__ int swz(int a) { return a ^ ((a >> 7) & 24); }

// ---------------------------------------------------------------------------
// build_F: fused (x0 | 2x-up x1 | 4x-up x2) feature, channel-last F[b][pos][c].
// LDS tile transpose: read side lane=pos (coalesced), write side float4 along c.
// Upsample matches jax.image.resize 'bilinear': src = (i+0.5)/s - 0.5, clamped.
// ---------------------------------------------------------------------------
__global__ __launch_bounds__(256) void build_F(const float* __restrict__ x0,
                                               const float* __restrict__ x1,
                                               const float* __restrict__ x2,
                                               float* __restrict__ F) {
    __shared__ float tile[64][65];           // [c_local][p_local], +1 pad
    const int ptile = blockIdx.x;            // 157 tiles of 64 positions
    const int ctile = blockIdx.y;            // 12 tiles of 64 channels
    const int b     = blockIdx.z;
    const int tid   = threadIdx.x;
    const int lane  = tid & 63;
    const int grp   = tid >> 6;              // 0..3

    const int pos = ptile*64 + lane;         // constant per thread
    const int level = ctile >> 2;            // 0: x0, 1: x1(2x), 2: x2(4x)
    const int cbase = (ctile & 3) * 64;      // channel offset within level

    if (pos < HH*WW) {
        if (level == 0) {
            const float* p = x0 + (size_t)b*CC*(HH*WW) + pos;
            #pragma unroll
            for (int r = 0; r < 16; ++r) {
                int c_local = r*4 + grp;
                tile[c_local][lane] = p[(size_t)(cbase + c_local)*(HH*WW)];
            }
        } else {
            const int   L = (level == 1) ? 50 : 25;
            const float s = (level == 1) ? 0.5f  : 0.25f;
            const float t = (level == 1) ? 0.25f : 0.375f;
            const float* src = (level == 1) ? x1 : x2;
            const int y = pos / WW, x = pos - (pos / WW) * WW;
            float cy = fminf(fmaxf((float)y * s - t, 0.0f), (float)(L - 1));
            float cx = fminf(fmaxf((float)x * s - t, 0.0f), (float)(L - 1));
            int yl = (int)cy, xl = (int)cx;
            int yh = min(yl + 1, L - 1), xh = min(xl + 1, L - 1);
            float fy = cy - (float)yl, fx = cx - (float)xl;
            float w00 = (1.0f-fy)*(1.0f-fx), w01 = (1.0f-fy)*fx;
            float w10 = fy*(1.0f-fx),        w11 = fy*fx;
            int o00 = yl*L+xl, o01 = yl*L+xh, o10 = yh*L+xl, o11 = yh*L+xh;
            const float* p = src + ((size_t)b*CC + cbase)*(size_t)(L*L);
            #pragma unroll
            for (int r = 0; r < 16; ++r) {
                int c_local = r*4 + grp;
                const float* q = p + (size_t)c_local*(L*L);
                tile[c_local][lane] = q[o00]*w00 + q[o01]*w01 + q[o10]*w10 + q[o11]*w11;
            }
        }
    }
    __syncthreads();

    // write: 16 lanes x float4 along c, 4 pos rows per wave; 2-way LDS alias (free)
    #pragma unroll
    for (int r = 0; r < 4; ++r) {
        int p_local = r*16 + (tid >> 4);
        int pp = ptile*64 + p_local;
        if (pp < HH*WW) {
            int c4 = (tid & 15) * 4;
            float4 v = make_float4(tile[c4+0][p_local], tile[c4+1][p_local],
                                   tile[c4+2][p_local], tile[c4+3][p_local]);
            *(float4*)(F + ((size_t)b*(HH*WW) + pp)*C3 + ctile*64 + c4) = v;
        }
    }
}

// ---------------------------------------------------------------------------
// roi3: block = (roi, 256-channel chunk), 256 threads = 64 slots x 4 bin-groups.
// Thread owns float4 of channels, ~13 bins -> all gathers are dwordx4 and the
// full [256ch][49bin] output tile is staged in LDS, written contiguously.
// ---------------------------------------------------------------------------
__global__ __launch_bounds__(256) void roi3(const float4* __restrict__ F4,
                                            const float* __restrict__ boxes,
                                            const float* __restrict__ ratio_hw,
                                            const float* __restrict__ offset_tl,
                                            float* __restrict__ out) {
    __shared__ float tile[256 * BINS];       // 50176 B, output layout (swizzled)
    __shared__ int   s_ylo[NSAMP], s_yhi[NSAMP], s_xlo[NSAMP], s_xhi[NSAMP];
    __shared__ float s_fy[NSAMP], s_fx[NSAMP];
    __shared__ int   s_vy[NSAMP], s_vx[NSAMP];

    const int tid   = threadIdx.x;
    const int k     = blockIdx.x;            // roi 0..511
    const int chunk = blockIdx.y;            // channel chunk 0..2
    const int b     = k >> 8;                // N=256

    if (tid < 2*NSAMP) {
        float r0 = ratio_hw[0], o0 = offset_tl[0];
        float scale = (float)HH / (1250.0f * r0 + 2.0f * o0);
        float rH  = ratio_hw[2*b],  rW   = ratio_hw[2*b + 1];
        float top = offset_tl[2*b], left = offset_tl[2*b + 1];
        const float* bx = boxes + (size_t)k * 4;
        bool isx = (tid >= NSAMP);
        int i = isx ? tid - NSAMP : tid;
        float a, e;
        if (isx) { a = (bx[0]*rW + left)*scale; e = (bx[2]*rW + left)*scale; }
        else     { a = (bx[1]*rH + top)*scale;  e = (bx[3]*rH + top)*scale;  }
        float len = fmaxf(e - a, 1.0f);       // ALIGNED=False
        float bs = len * (1.0f / (float)OUTB);
        float g = (float)(i >> 1) + 0.25f + 0.5f * (float)(i & 1);
        float p = a + g * bs;
        int v = (p >= -1.0f && p <= (float)HH) ? 1 : 0;
        float cc = fminf(fmaxf(p, 0.0f), (float)(HH - 1));
        int lo = (int)floorf(cc);
        int hi = min(lo + 1, HH - 1);
        float fr = cc - (float)lo;
        if (isx) { s_xlo[i] = lo; s_xhi[i] = hi; s_fx[i] = fr; s_vx[i] = v; }
        else     { s_ylo[i] = lo; s_yhi[i] = hi; s_fy[i] = fr; s_vy[i] = v; }
    }
    __syncthreads();

    const int slot = tid & 63;               // float4 channel slot within chunk
    const int bg   = tid >> 6;               // bin group 0..3
    const float4* Fb = F4 + (size_t)b*(HH*WW)*(C3/4) + chunk*64 + slot;

    for (int bin = bg; bin < BINS; bin += 4) {
        const int oy = bin / OUTB;
        const int ox = bin - oy*OUTB;
        float4 acc = make_float4(0.f, 0.f, 0.f, 0.f);
        #pragma unroll
        for (int sy = 0; sy < SR; ++sy) {
            const int iy = oy*SR + sy;
            const int yl = s_ylo[iy], yh = s_yhi[iy];
            const float fy = s_fy[iy];
            const int vy = s_vy[iy];
            #pragma unroll
            for (int sx = 0; sx < SR; ++sx) {
                const int ix = ox*SR + sx;
                if (vy && s_vx[ix]) {
                    const int xl = s_xlo[ix], xh = s_xhi[ix];
                    const float fx = s_fx[ix];
                    const float hy = 1.0f - fy, hx = 1.0f - fx;
                    const float w00 = hy*hx, w01 = hy*fx, w10 = fy*hx, w11 = fy*fx;
                    float4 v00 = Fb[(size_t)(yl*WW + xl)*(C3/4)];
                    float4 v01 = Fb[(size_t)(yl*WW + xh)*(C3/4)];
                    float4 v10 = Fb[(size_t)(yh*WW + xl)*(C3/4)];
                    float4 v11 = Fb[(size_t)(yh*WW + xh)*(C3/4)];
                    acc.x += v00.x*w00 + v01.x*w01 + v10.x*w10 + v11.x*w11;
                    acc.y += v00.y*w00 + v01.y*w01 + v10.y*w10 + v11.y*w11;
                    acc.z += v00.z*w00 + v01.z*w01 + v10.z*w10 + v11.z*w11;
                    acc.w += v00.w*w00 + v01.w*w01 + v10.w*w10 + v11.w*w11;
                }
            }
        }
        const int c0 = slot * 4;
        tile[swz((c0+0)*BINS + bin)] = acc.x * 0.25f;
        tile[swz((c0+1)*BINS + bin)] = acc.y * 0.25f;
        tile[swz((c0+2)*BINS + bin)] = acc.z * 0.25f;
        tile[swz((c0+3)*BINS + bin)] = acc.w * 0.25f;
    }
    __syncthreads();

    // One contiguous, fully-coalesced 50 KB write per block.
    float* dst = out + ((size_t)k*C3 + (size_t)chunk*256) * BINS;
    #pragma unroll 7
    for (int t = 0, i = tid; t < BINS; ++t, i += 256) {
        dst[i] = tile[swz(i)];
    }
}

// ---------------------------------------------------------------------------
// Fallback (no workspace): direct gather from sources, one float per thread.
// ---------------------------------------------------------------------------
__device__ __forceinline__ float feat_val(const float* __restrict__ x0,
                                          const float* __restrict__ x1,
                                          const float* __restrict__ x2,
                                          int b, int y, int x, int c) {
    if (c < CC) {
        return x0[(((size_t)b*CC + c)*HH + y)*WW + x];
    }
    const float* src;
    int L; float s, t; int cl;
    if (c < 2*CC) { src = x1; L = 50; s = 0.5f;  t = 0.25f;  cl = c - CC; }
    else          { src = x2; L = 25; s = 0.25f; t = 0.375f; cl = c - 2*CC; }
    float cy = fminf(fmaxf((float)y * s - t, 0.0f), (float)(L - 1));
    float cx = fminf(fmaxf((float)x * s - t, 0.0f), (float)(L - 1));
    int yl = (int)cy, xl = (int)cx;
    int yh = min(yl + 1, L - 1), xh = min(xl + 1, L - 1);
    float fy = cy - (float)yl, fx = cx - (float)xl;
    const float* p = src + (((size_t)b*CC + cl)*L)*L;
    float v00 = p[yl*L + xl], v01 = p[yl*L + xh];
    float v10 = p[yh*L + xl], v11 = p[yh*L + xh];
    float hy = 1.0f - fy, hx = 1.0f - fx;
    return v00*(hy*hx) + v01*(hy*fx) + v10*(fy*hx) + v11*(fy*fx);
}

__global__ __launch_bounds__(256) void roi_fallback(const float* __restrict__ x0,
                                                    const float* __restrict__ x1,
                                                    const float* __restrict__ x2,
                                                    const float* __restrict__ boxes,
                                                    const float* __restrict__ ratio_hw,
                                                    const float* __restrict__ offset_tl,
                                                    float* __restrict__ out) {
    __shared__ int   s_ylo[NSAMP], s_yhi[NSAMP], s_xlo[NSAMP], s_xhi[NSAMP];
    __shared__ float s_fy[NSAMP], s_fx[NSAMP];
    __shared__ int   s_vy[NSAMP], s_vx[NSAMP];

    const int tid = threadIdx.x;
    const int k = blockIdx.x;
    const int chunk = blockIdx.y;
    const int b = k >> 8;

    if (tid < 2*NSAMP) {
        float r0 = ratio_hw[0], o0 = offset_tl[0];
        float scale = (float)HH / (1250.0f * r0 + 2.0f * o0);
        float rH  = ratio_hw[2*b],  rW   = ratio_hw[2*b + 1];
        float top = offset_tl[2*b], left = offset_tl[2*b + 1];
        const float* bx = boxes + (size_t)k * 4;
        bool isx = (tid >= NSAMP);
        int i = isx ? tid - NSAMP : tid;
        float a, e;
        if (isx) { a = (bx[0]*rW + left)*scale; e = (bx[2]*rW + left)*scale; }
        else     { a = (bx[1]*rH + top)*scale;  e = (bx[3]*rH + top)*scale;  }
        float len = fmaxf(e - a, 1.0f);
        float bs = len * (1.0f / (float)OUTB);
        float g = (float)(i >> 1) + 0.25f + 0.5f * (float)(i & 1);
        float p = a + g * bs;
        int v = (p >= -1.0f && p <= (float)HH) ? 1 : 0;
        float cc = fminf(fmaxf(p, 0.0f), (float)(HH - 1));
        int lo = (int)floorf(cc);
        int hi = min(lo + 1, HH - 1);
        float fr = cc - (float)lo;
        if (isx) { s_xlo[i] = lo; s_xhi[i] = hi; s_fx[i] = fr; s_vx[i] = v; }
        else     { s_ylo[i] = lo; s_yhi[i] = hi; s_fy[i] = fr; s_vy[i] = v; }
    }
    __syncthreads();

    const int c = chunk * 256 + tid;
    for (int oy = 0; oy < OUTB; ++oy) {
        for (int ox = 0; ox < OUTB; ++ox) {
            float acc = 0.0f;
            #pragma unroll
            for (int sy = 0; sy < SR; ++sy) {
                const int iy = oy*SR + sy;
                #pragma unroll
                for (int sx = 0; sx < SR; ++sx) {
                    const int ix = ox*SR + sx;
                    if (s_vy[iy] && s_vx[ix]) {
                        const float fy = s_fy[iy], fx = s_fx[ix];
                        const float hy = 1.0f - fy, hx = 1.0f - fx;
                        float v00 = feat_val(x0,x1,x2,b, s_ylo[iy], s_xlo[ix], c);
                        float v01 = feat_val(x0,x1,x2,b, s_ylo[iy], s_xhi[ix], c);
                        float v10 = feat_val(x0,x1,x2,b, s_yhi[iy], s_xlo[ix], c);
                        float v11 = feat_val(x0,x1,x2,b, s_yhi[iy], s_xhi[ix], c);
                        acc += v00*(hy*hx) + v01*(hy*fx) + v10*(fy*hx) + v11*(fy*fx);
                    }
                }
            }
            out[(size_t)k*C3*BINS + (size_t)c*BINS + oy*OUTB + ox] = acc * 0.25f;
        }
    }
}

extern "C" void kernel_launch(void* const* d_in, const int* in_sizes, int n_in,
                              void* d_out, int out_size, void* d_ws, size_t ws_size,
                              hipStream_t stream) {
    const float* x0       = (const float*)d_in[0];
    const float* x1       = (const float*)d_in[1];
    const float* x2       = (const float*)d_in[2];
    const float* boxes    = (const float*)d_in[3];
    const float* ratio_hw = (const float*)d_in[4];
    const float* off_tl   = (const float*)d_in[5];
    float* out = (float*)d_out;

    const size_t needF = (size_t)BB * HH * WW * C3 * sizeof(float);  // 61.44 MB
    if (ws_size >= needF) {
        float* F = (float*)d_ws;
        build_F<<<dim3((HH*WW + 63)/64, C3/64, BB), 256, 0, stream>>>(x0, x1, x2, F);
        roi3<<<dim3(KK, 3), 256, 0, stream>>>((const float4*)F,
                                              boxes, ratio_hw, off_tl, out);
    } else {
        roi_fallback<<<dim3(KK, 3), 256, 0, stream>>>(x0, x1, x2,
                                                      boxes, ratio_hw, off_tl, out);
    }
}

// Round 4
// 99.722 us; speedup vs baseline: 3.4557x; 1.0167x over previous
//
#include <hip/hip_runtime.h>
#include <hip/hip_bf16.h>

// Problem constants (fixed by the reference's setup_inputs)
#define BB 2
#define CC 256      // channels per level
#define HH 100
#define WW 100
#define NN 256      // rois per batch
#define KK (BB*NN)  // 512 total rois
#define C3 (3*CC)   // 768 fused channels
#define OUTB 7
#define SR 2
#define NSAMP (OUTB*SR)   // 14 sample positions per axis
#define BINS (OUTB*OUTB)  // 49

// ---------------------------------------------------------------------------
// build_F: fused (x0 | 2x-up x1 | 4x-up x2) feature, channel-last F[b][pos][c].
// LDS tile transpose: read side coalesced along pos, write side float4 along c.
// Upsample matches jax.image.resize 'bilinear': src = (i+0.5)/s - 0.5, clamped.
// ---------------------------------------------------------------------------
__global__ __launch_bounds__(256) void build_F(const float* __restrict__ x0,
                                               const float* __restrict__ x1,
                                               const float* __restrict__ x2,
                                               float* __restrict__ F) {
    __shared__ float tile[64][65];           // [c_local][p_local], +1 pad
    const int ptile = blockIdx.x;            // 157 tiles of 64 positions
    const int ctile = blockIdx.y;            // 12 tiles of 64 channels
    const int b     = blockIdx.z;
    const int tid   = threadIdx.x;

    const int level = ctile >> 2;            // 0: x0, 1: x1(2x), 2: x2(4x)
    const int cbase = (ctile & 3) * 64;      // channel offset within level

    if (level == 0) {
        // float4 along pos: lane f (0..15) owns pos4 = f*4, c rows via loop.
        const int f  = tid & 15;
        const int cr = tid >> 4;             // 0..15
        const int p4 = ptile*64 + f*4;       // HH*WW % 4 == 0 -> all-or-nothing
        if (p4 + 3 < HH*WW) {
            const float* p = x0 + (size_t)b*CC*(HH*WW);
            #pragma unroll
            for (int r = 0; r < 4; ++r) {
                int c_local = r*16 + cr;
                float4 v = *(const float4*)(p + (size_t)(cbase + c_local)*(HH*WW) + p4);
                tile[c_local][f*4+0] = v.x;
                tile[c_local][f*4+1] = v.y;
                tile[c_local][f*4+2] = v.z;
                tile[c_local][f*4+3] = v.w;
            }
        }
    } else {
        const int lane = tid & 63;
        const int grp  = tid >> 6;           // 0..3
        const int pos  = ptile*64 + lane;
        if (pos < HH*WW) {
            const int   L = (level == 1) ? 50 : 25;
            const float s = (level == 1) ? 0.5f  : 0.25f;
            const float t = (level == 1) ? 0.25f : 0.375f;
            const float* src = (level == 1) ? x1 : x2;
            const int y = pos / WW, x = pos - (pos / WW) * WW;
            float cy = fminf(fmaxf((float)y * s - t, 0.0f), (float)(L - 1));
            float cx = fminf(fmaxf((float)x * s - t, 0.0f), (float)(L - 1));
            int yl = (int)cy, xl = (int)cx;
            int yh = min(yl + 1, L - 1), xh = min(xl + 1, L - 1);
            float fy = cy - (float)yl, fx = cx - (float)xl;
            float w00 = (1.0f-fy)*(1.0f-fx), w01 = (1.0f-fy)*fx;
            float w10 = fy*(1.0f-fx),        w11 = fy*fx;
            int o00 = yl*L+xl, o01 = yl*L+xh, o10 = yh*L+xl, o11 = yh*L+xh;
            const float* p = src + ((size_t)b*CC + cbase)*(size_t)(L*L);
            #pragma unroll
            for (int r = 0; r < 16; ++r) {
                int c_local = r*4 + grp;
                const float* q = p + (size_t)c_local*(L*L);
                tile[c_local][lane] = q[o00]*w00 + q[o01]*w01 + q[o10]*w10 + q[o11]*w11;
            }
        }
    }
    __syncthreads();

    // write: 16 lanes x float4 along c, 4 pos rows per wave
    #pragma unroll
    for (int r = 0; r < 4; ++r) {
        int p_local = r*16 + (tid >> 4);
        int pp = ptile*64 + p_local;
        if (pp < HH*WW) {
            int c4 = (tid & 15) * 4;
            float4 v = make_float4(tile[c4+0][p_local], tile[c4+1][p_local],
                                   tile[c4+2][p_local], tile[c4+3][p_local]);
            *(float4*)(F + ((size_t)b*(HH*WW) + pp)*C3 + ctile*64 + c4) = v;
        }
    }
}

// ---------------------------------------------------------------------------
// roi4: block = (roi, 128-channel chunk) -> 25.5 KB LDS -> 6 blocks/CU (75%).
// 256 threads = 32 float4-slots x 8 bin-groups. All gathers dwordx4.
// LDS tile [j][slot][51]: odd 51-dword stride -> store side is a 32-bank
// bijection (<=2 lanes/bank, free); read-out side consecutive (free).
// ---------------------------------------------------------------------------
__global__ __launch_bounds__(256, 6) void roi4(const float4* __restrict__ F4,
                                               const float* __restrict__ boxes,
                                               const float* __restrict__ ratio_hw,
                                               const float* __restrict__ offset_tl,
                                               float* __restrict__ out) {
    __shared__ float tile[4 * 32 * 51];      // 26112 B
    __shared__ int   s_ylo[NSAMP], s_yhi[NSAMP], s_xlo[NSAMP], s_xhi[NSAMP];
    __shared__ float s_fy[NSAMP], s_fx[NSAMP];
    __shared__ int   s_vy[NSAMP], s_vx[NSAMP];

    const int tid   = threadIdx.x;
    const int k     = blockIdx.x;            // roi 0..511
    const int chunk = blockIdx.y;            // channel chunk 0..5 (128 ch each)
    const int b     = k >> 8;                // N=256

    if (tid < 2*NSAMP) {
        float r0 = ratio_hw[0], o0 = offset_tl[0];
        float scale = (float)HH / (1250.0f * r0 + 2.0f * o0);
        float rH  = ratio_hw[2*b],  rW   = ratio_hw[2*b + 1];
        float top = offset_tl[2*b], left = offset_tl[2*b + 1];
        const float* bx = boxes + (size_t)k * 4;
        bool isx = (tid >= NSAMP);
        int i = isx ? tid - NSAMP : tid;
        float a, e;
        if (isx) { a = (bx[0]*rW + left)*scale; e = (bx[2]*rW + left)*scale; }
        else     { a = (bx[1]*rH + top)*scale;  e = (bx[3]*rH + top)*scale;  }
        float len = fmaxf(e - a, 1.0f);       // ALIGNED=False
        float bs = len * (1.0f / (float)OUTB);
        float g = (float)(i >> 1) + 0.25f + 0.5f * (float)(i & 1);
        float p = a + g * bs;
        int v = (p >= -1.0f && p <= (float)HH) ? 1 : 0;
        float cc = fminf(fmaxf(p, 0.0f), (float)(HH - 1));
        int lo = (int)floorf(cc);
        int hi = min(lo + 1, HH - 1);
        float fr = cc - (float)lo;
        if (isx) { s_xlo[i] = lo; s_xhi[i] = hi; s_fx[i] = fr; s_vx[i] = v; }
        else     { s_ylo[i] = lo; s_yhi[i] = hi; s_fy[i] = fr; s_vy[i] = v; }
    }
    __syncthreads();

    const int slot = tid & 31;               // float4 channel slot within chunk
    const int bg   = tid >> 5;               // bin group 0..7
    const float4* Fb = F4 + (size_t)b*(HH*WW)*(C3/4) + chunk*32 + slot;

    for (int bin = bg; bin < BINS; bin += 8) {
        const int oy = bin / OUTB;
        const int ox = bin - oy*OUTB;
        float4 acc = make_float4(0.f, 0.f, 0.f, 0.f);
        #pragma unroll
        for (int sy = 0; sy < SR; ++sy) {
            const int iy = oy*SR + sy;
            const int yl = s_ylo[iy], yh = s_yhi[iy];
            const float fy = s_fy[iy];
            const int vy = s_vy[iy];
            #pragma unroll
            for (int sx = 0; sx < SR; ++sx) {
                const int ix = ox*SR + sx;
                if (vy && s_vx[ix]) {
                    const int xl = s_xlo[ix], xh = s_xhi[ix];
                    const float fx = s_fx[ix];
                    const float hy = 1.0f - fy, hx = 1.0f - fx;
                    const float w00 = hy*hx, w01 = hy*fx, w10 = fy*hx, w11 = fy*fx;
                    float4 v00 = Fb[(size_t)(yl*WW + xl)*(C3/4)];
                    float4 v01 = Fb[(size_t)(yl*WW + xh)*(C3/4)];
                    float4 v10 = Fb[(size_t)(yh*WW + xl)*(C3/4)];
                    float4 v11 = Fb[(size_t)(yh*WW + xh)*(C3/4)];
                    acc.x += v00.x*w00 + v01.x*w01 + v10.x*w10 + v11.x*w11;
                    acc.y += v00.y*w00 + v01.y*w01 + v10.y*w10 + v11.y*w11;
                    acc.z += v00.z*w00 + v01.z*w01 + v10.z*w10 + v11.z*w11;
                    acc.w += v00.w*w00 + v01.w*w01 + v10.w*w10 + v11.w*w11;
                }
            }
        }
        // channel c = slot*4 + j -> tile[j][slot][bin], row stride 51 (odd)
        tile[0*32*51 + slot*51 + bin] = acc.x * 0.25f;
        tile[1*32*51 + slot*51 + bin] = acc.y * 0.25f;
        tile[2*32*51 + slot*51 + bin] = acc.z * 0.25f;
        tile[3*32*51 + slot*51 + bin] = acc.w * 0.25f;
    }
    __syncthreads();

    // One contiguous, fully-coalesced 25 KB write per block.
    float* dst = out + ((size_t)k*C3 + (size_t)chunk*128) * BINS;
    for (int i = tid; i < 128*BINS; i += 256) {
        const int c = i / BINS;              // local channel 0..127
        const int bin = i - c*BINS;
        dst[i] = tile[(c & 3)*32*51 + (c >> 2)*51 + bin];
    }
}

// ---------------------------------------------------------------------------
// Fallback (no workspace): direct gather from sources, one float per thread.
// ---------------------------------------------------------------------------
__device__ __forceinline__ float feat_val(const float* __restrict__ x0,
                                          const float* __restrict__ x1,
                                          const float* __restrict__ x2,
                                          int b, int y, int x, int c) {
    if (c < CC) {
        return x0[(((size_t)b*CC + c)*HH + y)*WW + x];
    }
    const float* src;
    int L; float s, t; int cl;
    if (c < 2*CC) { src = x1; L = 50; s = 0.5f;  t = 0.25f;  cl = c - CC; }
    else          { src = x2; L = 25; s = 0.25f; t = 0.375f; cl = c - 2*CC; }
    float cy = fminf(fmaxf((float)y * s - t, 0.0f), (float)(L - 1));
    float cx = fminf(fmaxf((float)x * s - t, 0.0f), (float)(L - 1));
    int yl = (int)cy, xl = (int)cx;
    int yh = min(yl + 1, L - 1), xh = min(xl + 1, L - 1);
    float fy = cy - (float)yl, fx = cx - (float)xl;
    const float* p = src + (((size_t)b*CC + cl)*L)*L;
    float v00 = p[yl*L + xl], v01 = p[yl*L + xh];
    float v10 = p[yh*L + xl], v11 = p[yh*L + xh];
    float hy = 1.0f - fy, hx = 1.0f - fx;
    return v00*(hy*hx) + v01*(hy*fx) + v10*(fy*hx) + v11*(fy*fx);
}

__global__ __launch_bounds__(256) void roi_fallback(const float* __restrict__ x0,
                                                    const float* __restrict__ x1,
                                                    const float* __restrict__ x2,
                                                    const float* __restrict__ boxes,
                                                    const float* __restrict__ ratio_hw,
                                                    const float* __restrict__ offset_tl,
                                                    float* __restrict__ out) {
    __shared__ int   s_ylo[NSAMP], s_yhi[NSAMP], s_xlo[NSAMP], s_xhi[NSAMP];
    __shared__ float s_fy[NSAMP], s_fx[NSAMP];
    __shared__ int   s_vy[NSAMP], s_vx[NSAMP];

    const int tid = threadIdx.x;
    const int k = blockIdx.x;
    const int chunk = blockIdx.y;
    const int b = k >> 8;

    if (tid < 2*NSAMP) {
        float r0 = ratio_hw[0], o0 = offset_tl[0];
        float scale = (float)HH / (1250.0f * r0 + 2.0f * o0);
        float rH  = ratio_hw[2*b],  rW   = ratio_hw[2*b + 1];
        float top = offset_tl[2*b], left = offset_tl[2*b + 1];
        const float* bx = boxes + (size_t)k * 4;
        bool isx = (tid >= NSAMP);
        int i = isx ? tid - NSAMP : tid;
        float a, e;
        if (isx) { a = (bx[0]*rW + left)*scale; e = (bx[2]*rW + left)*scale; }
        else     { a = (bx[1]*rH + top)*scale;  e = (bx[3]*rH + top)*scale;  }
        float len = fmaxf(e - a, 1.0f);
        float bs = len * (1.0f / (float)OUTB);
        float g = (float)(i >> 1) + 0.25f + 0.5f * (float)(i & 1);
        float p = a + g * bs;
        int v = (p >= -1.0f && p <= (float)HH) ? 1 : 0;
        float cc = fminf(fmaxf(p, 0.0f), (float)(HH - 1));
        int lo = (int)floorf(cc);
        int hi = min(lo + 1, HH - 1);
        float fr = cc - (float)lo;
        if (isx) { s_xlo[i] = lo; s_xhi[i] = hi; s_fx[i] = fr; s_vx[i] = v; }
        else     { s_ylo[i] = lo; s_yhi[i] = hi; s_fy[i] = fr; s_vy[i] = v; }
    }
    __syncthreads();

    const int c = chunk * 256 + tid;
    for (int oy = 0; oy < OUTB; ++oy) {
        for (int ox = 0; ox < OUTB; ++ox) {
            float acc = 0.0f;
            #pragma unroll
            for (int sy = 0; sy < SR; ++sy) {
                const int iy = oy*SR + sy;
                #pragma unroll
                for (int sx = 0; sx < SR; ++sx) {
                    const int ix = ox*SR + sx;
                    if (s_vy[iy] && s_vx[ix]) {
                        const float fy = s_fy[iy], fx = s_fx[ix];
                        const float hy = 1.0f - fy, hx = 1.0f - fx;
                        float v00 = feat_val(x0,x1,x2,b, s_ylo[iy], s_xlo[ix], c);
                        float v01 = feat_val(x0,x1,x2,b, s_ylo[iy], s_xhi[ix], c);
                        float v10 = feat_val(x0,x1,x2,b, s_yhi[iy], s_xlo[ix], c);
                        float v11 = feat_val(x0,x1,x2,b, s_yhi[iy], s_xhi[ix], c);
                        acc += v00*(hy*hx) + v01*(hy*fx) + v10*(fy*hx) + v11*(fy*fx);
                    }
                }
            }
            out[(size_t)k*C3*BINS + (size_t)c*BINS + oy*OUTB + ox] = acc * 0.25f;
        }
    }
}

extern "C" void kernel_launch(void* const* d_in, const int* in_sizes, int n_in,
                              void* d_out, int out_size, void* d_ws, size_t ws_size,
                              hipStream_t stream) {
    const float* x0       = (const float*)d_in[0];
    const float* x1       = (const float*)d_in[1];
    const float* x2       = (const float*)d_in[2];
    const float* boxes    = (const float*)d_in[3];
    const float* ratio_hw = (const float*)d_in[4];
    const float* off_tl   = (const float*)d_in[5];
    float* out = (float*)d_out;

    const size_t needF = (size_t)BB * HH * WW * C3 * sizeof(float);  // 61.44 MB
    if (ws_size >= needF) {
        float* F = (float*)d_ws;
        build_F<<<dim3((HH*WW + 63)/64, C3/64, BB), 256, 0, stream>>>(x0, x1, x2, F);
        roi4<<<dim3(KK, 6), 256, 0, stream>>>((const float4*)F,
                                              boxes, ratio_hw, off_tl, out);
    } else {
        roi_fallback<<<dim3(KK, 3), 256, 0, stream>>>(x0, x1, x2,
                                                      boxes, ratio_hw, off_tl, out);
    }
}